// Round 1
// baseline (692.734 us; speedup 1.0000x reference)
//
#include <hip/hip_runtime.h>

// Problem constants (from reference setup_inputs)
#define BB 4
#define MM 16384
#define NN 32768
#define KK 16
#define ROWS (BB * NN)   // 131072
#define OUTW 131         // 3 coords + 64 + 64
#define RPW 32           // rows per wave
#define GRID_A 1024      // 4 waves/block * 32 rows = 128 rows/block; 4 blocks/CU exact
#define GRID_B 1024

// ws layout: [0:64] sum1 [64:128] sq1 [128:192] sum2 [192:256] sq2
//            int counters at ((int*)ws)[256] (kernel A) and [257] (kernel B)

__device__ __forceinline__ float bcast(float v, int sl) {
    // wave-uniform broadcast via v_readlane (sl is a literal after unroll)
    return __int_as_float(__builtin_amdgcn_readlane(__float_as_int(v), sl));
}

// Software grid barrier. SAFE ONLY because grid == 4 blocks/CU * 256 CUs and
// __launch_bounds__(256,4) + LDS 33 KB guarantee 4 blocks/CU co-residency.
__device__ __forceinline__ void grid_barrier(int* bar, int nblk) {
    __threadfence();          // drain this thread's agent-scope atomics
    __syncthreads();
    if (threadIdx.x == 0) {
        __hip_atomic_fetch_add(bar, 1, __ATOMIC_ACQ_REL, __HIP_MEMORY_SCOPE_AGENT);
        while (__hip_atomic_load(bar, __ATOMIC_ACQUIRE, __HIP_MEMORY_SCOPE_AGENT) < nblk)
            __builtin_amdgcn_s_sleep(8);
    }
    __syncthreads();
}

// ---------------------------------------------------------------------------
// Kernel A: gather + max-pool + (pooled @ W1 + b1), stats, grid-sync, BN+ReLU
//           writes out[..., 0:3] (coords) and out[..., 3:67]
// XCD swizzle: block w -> XCD w&7 (empirical round-robin); give each batch
// 2 XCDs so gathers hit a 4.2 MB cf slice resident in that XCD's 4 MB L2.
// ---------------------------------------------------------------------------
__global__ __launch_bounds__(256, 4) void k_pool_proj(
    const float* __restrict__ cf, const int* __restrict__ idxs,
    const float* __restrict__ scoord,
    const float* __restrict__ W1, const float* __restrict__ b1,
    const float* __restrict__ g1, const float* __restrict__ be1,
    float* __restrict__ out, float* __restrict__ ws)
{
    __shared__ float ysav[4][RPW][64];   // 32 KB: per-wave y tile
    __shared__ float lsum[64], lsq[64];
    const int lane = threadIdx.x & 63;
    const int wv   = threadIdx.x >> 6;
    if (threadIdx.x < 64) { lsum[threadIdx.x] = 0.f; lsq[threadIdx.x] = 0.f; }
    __syncthreads();

    const int w     = blockIdx.x;
    const int xcd   = w & 7;
    const int batch = xcd >> 1;                      // 2 XCDs per batch
    const int lb    = (w >> 3) + ((xcd & 1) << 7);   // [0,256) within batch
    const int rbase = batch * NN + (lb * 4 + wv) * RPW;

    float wr[64];                                    // W1 column for this lane
#pragma unroll
    for (int c = 0; c < 64; ++c) wr[c] = W1[c * 64 + lane];
    const float bias = b1[lane];
    const float* cfb = cf + ((size_t)batch * MM * 64);

    float psum = 0.f, psq = 0.f;
    int mi4 = idxs[(size_t)rbase * KK + lane];       // 4 rows' indices per wave-load
    for (int r0 = 0; r0 < RPW; r0 += 4) {
        int mi4n = 0;
        if (r0 + 4 < RPW) mi4n = idxs[(size_t)(rbase + r0 + 4) * KK + lane];
#pragma unroll
        for (int rr = 0; rr < 4; ++rr) {
            // gather + max over K=16 neighbors; indices broadcast via readlane
            // -> SGPR base, loads are saddr + (lane<<2). Two fmax chains.
            float p0 = -3.402823466e38f, p1 = p0;
#pragma unroll
            for (int k = 0; k < KK; k += 2) {
                const int m0 = __builtin_amdgcn_readlane(mi4, (rr << 4) + k);
                const int m1 = __builtin_amdgcn_readlane(mi4, (rr << 4) + k + 1);
                p0 = fmaxf(p0, cfb[((size_t)m0 << 6) + lane]);
                p1 = fmaxf(p1, cfb[((size_t)m1 << 6) + lane]);
            }
            const float pmax = fmaxf(p0, p1);
            // y[lane] = b + sum_c pool[c] * W1[c][lane]; pool[c] lives in lane c.
            // 4 independent FMA chains, broadcast via v_readlane (no LDS).
            float a0 = 0.f, a1 = 0.f, a2 = 0.f, a3 = 0.f;
#pragma unroll
            for (int c = 0; c < 64; c += 4) {
                a0 = fmaf(bcast(pmax, c + 0), wr[c + 0], a0);
                a1 = fmaf(bcast(pmax, c + 1), wr[c + 1], a1);
                a2 = fmaf(bcast(pmax, c + 2), wr[c + 2], a2);
                a3 = fmaf(bcast(pmax, c + 3), wr[c + 3], a3);
            }
            const float y = bias + ((a0 + a1) + (a2 + a3));
            ysav[wv][r0 + rr][lane] = y;
            psum += y; psq += y * y;
            const int r = rbase + r0 + rr;
            if (lane < 3) out[(size_t)r * OUTW + lane] = scoord[(size_t)r * 3 + lane];
        }
        mi4 = mi4n;
    }

    atomicAdd(&lsum[lane], psum);
    atomicAdd(&lsq[lane], psq);
    __syncthreads();
    if (threadIdx.x < 64) {
        atomicAdd(&ws[threadIdx.x],      lsum[threadIdx.x]);
        atomicAdd(&ws[64 + threadIdx.x], lsq[threadIdx.x]);
    }

    grid_barrier((int*)ws + 256, GRID_A);

    // fold k_stats per-lane: a = g*rsqrt(var+eps), c0 = beta - mu*a
    const float inv = 1.0f / (float)ROWS;
    const float s  = __hip_atomic_load(&ws[lane],      __ATOMIC_RELAXED, __HIP_MEMORY_SCOPE_AGENT);
    const float q  = __hip_atomic_load(&ws[64 + lane], __ATOMIC_RELAXED, __HIP_MEMORY_SCOPE_AGENT);
    const float m  = s * inv;
    const float v  = q * inv - m * m;
    const float a  = g1[lane] * rsqrtf(v + 1e-5f);
    const float c0 = be1[lane] - m * a;
    for (int r0 = 0; r0 < RPW; ++r0) {
        const float y = ysav[wv][r0][lane];
        out[(size_t)(rbase + r0) * OUTW + 3 + lane] = fmaxf(fmaf(y, a, c0), 0.f);
    }
}

// ---------------------------------------------------------------------------
// Kernel B: (skip_feat @ W2 + b2), stats, grid-sync, BN+ReLU -> out[..., 67:131]
// float4 input loads: one dwordx4 per lane covers 4 rows per wave.
// ---------------------------------------------------------------------------
__global__ __launch_bounds__(256, 4) void k_skip_proj(
    const float* __restrict__ sf,
    const float* __restrict__ W2, const float* __restrict__ b2,
    const float* __restrict__ g2, const float* __restrict__ be2,
    float* __restrict__ out, float* __restrict__ ws)
{
    __shared__ float ysav[4][RPW][64];
    __shared__ float lsum[64], lsq[64];
    const int lane = threadIdx.x & 63;
    const int wv   = threadIdx.x >> 6;
    if (threadIdx.x < 64) { lsum[threadIdx.x] = 0.f; lsq[threadIdx.x] = 0.f; }
    __syncthreads();

    const int rbase = (blockIdx.x * 4 + wv) * RPW;

    float wr[64];
#pragma unroll
    for (int c = 0; c < 64; ++c) wr[c] = W2[c * 64 + lane];
    const float bias = b2[lane];

    const float4* sf4 = (const float4*)sf;
    float psum = 0.f, psq = 0.f;
    // 4-row group: lane l holds row rbase+g+(l>>4), channels 4*(l&15)..+3
    float4 x4 = sf4[(size_t)rbase * 16 + lane];
    for (int g = 0; g < RPW; g += 4) {
        float4 x4n = make_float4(0.f, 0.f, 0.f, 0.f);
        if (g + 4 < RPW) x4n = sf4[(size_t)(rbase + g + 4) * 16 + lane];
#pragma unroll
        for (int rr = 0; rr < 4; ++rr) {
            float a0 = 0.f, a1 = 0.f, a2 = 0.f, a3 = 0.f;
#pragma unroll
            for (int c = 0; c < 64; c += 4) {
                const int sl = rr * 16 + (c >> 2);   // source lane for ch c..c+3 of row rr
                a0 = fmaf(bcast(x4.x, sl), wr[c + 0], a0);
                a1 = fmaf(bcast(x4.y, sl), wr[c + 1], a1);
                a2 = fmaf(bcast(x4.z, sl), wr[c + 2], a2);
                a3 = fmaf(bcast(x4.w, sl), wr[c + 3], a3);
            }
            const float y = bias + ((a0 + a1) + (a2 + a3));
            ysav[wv][g + rr][lane] = y;
            psum += y; psq += y * y;
        }
        x4 = x4n;
    }

    atomicAdd(&lsum[lane], psum);
    atomicAdd(&lsq[lane], psq);
    __syncthreads();
    if (threadIdx.x < 64) {
        atomicAdd(&ws[128 + threadIdx.x], lsum[threadIdx.x]);
        atomicAdd(&ws[192 + threadIdx.x], lsq[threadIdx.x]);
    }

    grid_barrier((int*)ws + 257, GRID_B);

    const float inv = 1.0f / (float)ROWS;
    const float s  = __hip_atomic_load(&ws[128 + lane], __ATOMIC_RELAXED, __HIP_MEMORY_SCOPE_AGENT);
    const float q  = __hip_atomic_load(&ws[192 + lane], __ATOMIC_RELAXED, __HIP_MEMORY_SCOPE_AGENT);
    const float m  = s * inv;
    const float v  = q * inv - m * m;
    const float a  = g2[lane] * rsqrtf(v + 1e-5f);
    const float c0 = be2[lane] - m * a;
    for (int r0 = 0; r0 < RPW; ++r0) {
        const float y = ysav[wv][r0][lane];
        out[(size_t)(rbase + r0) * OUTW + 67 + lane] = fmaxf(fmaf(y, a, c0), 0.f);
    }
}

// ---------------------------------------------------------------------------
extern "C" void kernel_launch(void* const* d_in, const int* in_sizes, int n_in,
                              void* d_out, int out_size, void* d_ws, size_t ws_size,
                              hipStream_t stream)
{
    const float* cf     = (const float*)d_in[1];   // curr_feat (B,M,64)
    const float* scoord = (const float*)d_in[2];   // skip_coords (B,N,3)
    const float* sf     = (const float*)d_in[3];   // skip_feat (B,N,64)
    const int*   idxs   = (const int*)  d_in[4];   // upsampling_idxs (B,N,16)
    const float* W1     = (const float*)d_in[5];
    const float* b1     = (const float*)d_in[6];
    const float* g1     = (const float*)d_in[7];
    const float* be1    = (const float*)d_in[8];
    const float* W2     = (const float*)d_in[9];
    const float* b2     = (const float*)d_in[10];
    const float* g2     = (const float*)d_in[11];
    const float* be2    = (const float*)d_in[12];
    float* out = (float*)d_out;
    float* ws  = (float*)d_ws;

    // zero stats (256 floats) + both barrier counters
    hipMemsetAsync(ws, 0, 2048, stream);
    k_pool_proj<<<GRID_A, 256, 0, stream>>>(cf, idxs, scoord, W1, b1, g1, be1, out, ws);
    k_skip_proj<<<GRID_B, 256, 0, stream>>>(sf, W2, b2, g2, be2, out, ws);
}